// Round 10
// baseline (321.399 us; speedup 1.0000x reference)
//
#include <hip/hip_runtime.h>
#include <hip/hip_bf16.h>

// Problem constants
constexpr int Bb = 8, Ll = 2048, Ww = 1024;
constexpr int BL = Bb * Ll;              // 16384

typedef short bf16x8 __attribute__((ext_vector_type(8)));
typedef float f32x4  __attribute__((ext_vector_type(4)));

// ---------- bf16 helpers ----------
__device__ inline unsigned short f2bf(float f) {
    union { float f; unsigned u; } v; v.f = f;
    unsigned u = v.u;
    unsigned r = (u + 0x7fffu + ((u >> 16) & 1u)) >> 16;
    return (unsigned short)r;
}
// lerp two packed bf16 pairs (lo=even ch, hi=odd ch) -> packed bf16 pair
__device__ inline unsigned lerp_pair(unsigned pa, unsigned pb, float w0, float w1) {
    union { unsigned u; float f; } alo, ahi, blo, bhi;
    alo.u = pa << 16;  ahi.u = pa & 0xffff0000u;
    blo.u = pb << 16;  bhi.u = pb & 0xffff0000u;
    float hlo = w0 * alo.f + w1 * blo.f;
    float hhi = w0 * ahi.f + w1 * bhi.f;
    union { __hip_bfloat162 h2; unsigned u; } r;
    r.h2 = __float22bfloat162_rn(float2{hlo, hhi});
    return r.u;
}

// ---------- async global->LDS, 16B per lane ----------
__device__ inline void gl_lds16(const unsigned short* g, unsigned short* l) {
    __builtin_amdgcn_global_load_lds(
        (const __attribute__((address_space(1))) unsigned int*)g,
        (__attribute__((address_space(3))) unsigned int*)l, 16, 0, 0);
}

// ---------- kernel 1: FUSED preprocessing ----------
// blocks [0, 4096)        : offsets path  (x -> x_bf, pk)   [w_off via LDS transpose]
// blocks [4096, 4352)     : wconv path    (conv_w -> w_t pre-tiled swizzled bf16)
// blocks [4352, 4368)     : mask path     (mask -> maskf; per-block local dtype detect)
__global__ __launch_bounds__(256) void prep_kernel(
    const float* __restrict__ x, const float* __restrict__ w_off, const float* __restrict__ b_off,
    const float* __restrict__ conv_w, const void* __restrict__ mraw,
    unsigned short* __restrict__ x_bf, float4* __restrict__ pk,
    unsigned short* __restrict__ w_t, float* __restrict__ maskf)
{
    const int blk = blockIdx.x;
    const int tid = threadIdx.x;
    __shared__ float wt[5][1024];     // transposed w_off (20 KB), offsets path only

    if (blk < 4096) {
        // ---- cooperative transposed load of w_off: coalesced float4 reads ----
        #pragma unroll
        for (int r = 0; r < 5; ++r) {
            const int f4 = tid + 256 * r;            // float4 index 0..1279
            float4 v = *(const float4*)&w_off[f4 * 4];
            const int idx = f4 * 4;
            const float* ve = (const float*)&v;
            #pragma unroll
            for (int e = 0; e < 4; ++e) {
                const int li = idx + e;
                wt[li % 5][li / 5] = ve[e];
            }
        }

        // ---- offsets + x -> bf16 (one wave per row) ----
        const int wave = tid >> 6, lane = tid & 63;
        const int bl = blk * 4 + wave;
        const int l = bl & (Ll - 1);
        const int c0 = lane * 16;

        const float* xr = x + (size_t)bl * Ww + c0;
        float4 v0 = *(const float4*)(xr + 0);
        float4 v1 = *(const float4*)(xr + 4);
        float4 v2 = *(const float4*)(xr + 8);
        float4 v3 = *(const float4*)(xr + 12);
        float xv[16] = { v0.x,v0.y,v0.z,v0.w, v1.x,v1.y,v1.z,v1.w,
                         v2.x,v2.y,v2.z,v2.w, v3.x,v3.y,v3.z,v3.w };

        uint4 pa, pb;
        unsigned* pu = (unsigned*)&pa;
        #pragma unroll
        for (int j = 0; j < 4; j++) pu[j] = (unsigned)f2bf(xv[j*2]) | ((unsigned)f2bf(xv[j*2+1]) << 16);
        pu = (unsigned*)&pb;
        #pragma unroll
        for (int j = 0; j < 4; j++) pu[j] = (unsigned)f2bf(xv[8+j*2]) | ((unsigned)f2bf(xv[8+j*2+1]) << 16);
        *(uint4*)&x_bf[(size_t)bl * Ww + c0]     = pa;
        *(uint4*)&x_bf[(size_t)bl * Ww + c0 + 8] = pb;

        // ---- re-scan row with stride-64 lane mapping (coalesced, L1-hot) ----
        float xs[16];
        const float* xrow = x + (size_t)bl * Ww;
        #pragma unroll
        for (int jj = 0; jj < 16; jj++) xs[jj] = xrow[lane + 64 * jj];

        __syncthreads();     // wt ready (uniform branch: all threads of block here)

        float acc[5] = {0.f, 0.f, 0.f, 0.f, 0.f};
        #pragma unroll
        for (int jj = 0; jj < 16; jj++) {
            const int c = lane + 64 * jj;
            #pragma unroll
            for (int k = 0; k < 5; k++) acc[k] += xs[jj] * wt[k][c];
        }
        #pragma unroll
        for (int k = 0; k < 5; k++)
            #pragma unroll
            for (int off = 32; off; off >>= 1) acc[k] += __shfl_xor(acc[k], off);

        if (lane < 5) {
            float s = (lane == 0) ? acc[0] : (lane == 1) ? acc[1] : (lane == 2) ? acc[2]
                    : (lane == 3) ? acc[3] : acc[4];
            s += b_off[lane];
            float offv = tanhf(s) * 2.0f;
            float pos = (float)l + (float)(lane - 2) + offv;
            float p0 = floorf(pos);
            float frac = pos - p0;
            int i0 = (int)p0;
            int i1 = i0 + 1;
            int ok0 = (i0 >= 0) && (i0 < Ll);
            int ok1 = (i1 >= 0) && (i1 < Ll);
            float4 pkv;
            pkv.x = __int_as_float(min(max(i0, 0), Ll - 1));
            pkv.y = __int_as_float(min(max(i1, 0), Ll - 1));
            pkv.z = ok0 ? (1.0f - frac) : 0.0f;
            pkv.w = ok1 ? frac : 0.0f;
            pk[bl * 5 + lane] = pkv;
        }
    } else if (blk < 4352) {
        // ---- conv_w fp32 [g][o][c][k] -> pre-tiled swizzled bf16 images ----
        // Swizzle uses row bits [2:1] so a 16-lane ds_read quarter spreads over all
        // 8 16B-groups 2x (2-way = free).
        int t = (blk - 4096) * 256 + tid;            // 0..65535
        int oct = t & 63;
        int o   = (t >> 6) & 511;
        int g   = t >> 15;
        const float* src = conv_w + ((size_t)(g * 512 + o) * 512 + oct * 8) * 5;
        float f[40];
        #pragma unroll
        for (int j = 0; j < 10; j++) *(float4*)&f[j * 4] = *(const float4*)&src[j * 4];
        int r = o & 127, ob = o >> 7, cs = oct >> 2, q = oct & 3;
        int base16 = ((g * 20 + ob) * 16 + cs) * 512 + r * 4 + (q ^ ((r >> 1) & 3));
        #pragma unroll
        for (int k = 0; k < 5; k++) {
            ushort4 lo, hi;
            lo.x = f2bf(f[0 * 5 + k]); lo.y = f2bf(f[1 * 5 + k]);
            lo.z = f2bf(f[2 * 5 + k]); lo.w = f2bf(f[3 * 5 + k]);
            hi.x = f2bf(f[4 * 5 + k]); hi.y = f2bf(f[5 * 5 + k]);
            hi.z = f2bf(f[6 * 5 + k]); hi.w = f2bf(f[7 * 5 + k]);
            int dst16 = base16 + k * 4 * 16 * 512;
            *(ushort4*)&w_t[(size_t)dst16 * 8]     = lo;
            *(ushort4*)&w_t[(size_t)dst16 * 8 + 4] = hi;
        }
    } else {
        // ---- mask expand; each block re-derives dtype flags locally (no cross-block dep)
        const unsigned char* mb = (const unsigned char*)mraw;
        const unsigned* mw = (const unsigned*)mraw;
        int nonint = 0, notf = 0, hasf = 0;
        for (int i = tid; i < BL; i += 256) { if ((i & 3) && mb[i]) nonint = 1; }
        for (int i = tid; i < BL / 4; i += 256) {
            unsigned w = mw[i];
            if (w == 0x3f800000u) hasf = 1; else if (w) notf = 1;
        }
        __shared__ int sf[3];
        if (tid == 0) { sf[0] = 0; sf[1] = 0; sf[2] = 0; }
        __syncthreads();
        if (nonint) atomicOr(&sf[0], 1);
        if (notf)   atomicOr(&sf[1], 1);
        if (hasf)   atomicOr(&sf[2], 1);
        __syncthreads();
        const int is_f32  = (!sf[1]) && sf[2];
        const int is_bool = (!is_f32) && sf[0];
        const int gid = (blk - 4352) * 256 + tid;    // 4096 threads total over 16 blocks
        for (int i = gid; i < BL; i += 4096) {
            int masked = is_bool ? (mb[i] != 0) : (mw[i] != 0u);
            maskf[i] = masked ? 0.0f : 1.0f;
        }
    }
}

// ---------- kernel 2: fused deform GEMM -> h. Block = 128 rows x 256 cols. ----------
// R4-proven 128-row structure (LDS A-build 2 chunks/thread, runtime buf,
// __syncthreads) + R9 conflict-free B swizzle + __launch_bounds__(256,3):
// 48KB LDS x 3 blocks/CU = 12 waves (same occupancy as the 64-row tile) but
// 32 MFMA per wave-barrier and HALF the barrier-drain events (160 vs 320
// block-iters per CU).
__global__ __launch_bounds__(256, 3) void gemm_kernel(
    const unsigned short* __restrict__ x_bf, const unsigned short* __restrict__ w_t,
    const float4* __restrict__ pk, const float* __restrict__ conv_b,
    unsigned short* __restrict__ h)
{
    __shared__ unsigned short Bs[2][2 * 4096];   // 2 x 16KB = 32 KB
    __shared__ unsigned short As[2][4096];       // 2 x  8KB = 16 KB
    const int tid = threadIdx.x;
    const int mt = blockIdx.x;            // 0..127
    const int nhalf = blockIdx.y;         // 0..1
    const int g = blockIdx.z;             // 0..1
    const int b = mt >> 4;
    const int lane = tid & 63, wave = tid >> 6;
    const int wr4 = (wave >> 1) * 4;      // row-block base (16-row units) for compute
    const int imgsel = wave & 1;          // column 128-block within the 256
    const int l15 = lane & 15, l4 = lane >> 4;
    const int sw = (l4 ^ ((l15 >> 1) & 3)) * 8;   // conflict-free B-read swizzle

    // builder role: this thread fills chunks tid and tid+256 of the A tile
    const int arow = ((tid >> 6) << 4) + (tid & 15);   // 0..63
    const int oct8 = ((tid >> 4) & 3) * 8;             // ch-octet within 32-chunk
    const int bl_a = mt * 128 + arow;
    const int bl_b = bl_a + 64;
    const int gbase = g * 512;

    unsigned off0a, off1a, off0b, off1b;
    float w0a, w1a, w0b, w1b;
    auto load_meta = [&](int k2) {
        float4 pa = pk[bl_a * 5 + k2];
        float4 pb = pk[bl_b * 5 + k2];
        off0a = (unsigned)(((b << 11) + __float_as_int(pa.x)) * Ww + gbase);
        off1a = (unsigned)(((b << 11) + __float_as_int(pa.y)) * Ww + gbase);
        w0a = pa.z; w1a = pa.w;
        off0b = (unsigned)(((b << 11) + __float_as_int(pb.x)) * Ww + gbase);
        off1b = (unsigned)(((b << 11) + __float_as_int(pb.y)) * Ww + gbase);
        w0b = pb.z; w1b = pb.w;
    };
    auto build_A = [&](int cs2, unsigned short* dst) {
        const int ch = cs2 * 32 + oct8;
        uint4 ua = *(const uint4*)(x_bf + off0a + ch);
        uint4 ub = *(const uint4*)(x_bf + off1a + ch);
        uint4 uc = *(const uint4*)(x_bf + off0b + ch);
        uint4 ud = *(const uint4*)(x_bf + off1b + ch);
        uint4 ra, rb;
        ra.x = lerp_pair(ua.x, ub.x, w0a, w1a);
        ra.y = lerp_pair(ua.y, ub.y, w0a, w1a);
        ra.z = lerp_pair(ua.z, ub.z, w0a, w1a);
        ra.w = lerp_pair(ua.w, ub.w, w0a, w1a);
        rb.x = lerp_pair(uc.x, ud.x, w0b, w1b);
        rb.y = lerp_pair(uc.y, ud.y, w0b, w1b);
        rb.z = lerp_pair(uc.z, ud.z, w0b, w1b);
        rb.w = lerp_pair(uc.w, ud.w, w0b, w1b);
        *(uint4*)&dst[tid * 8]         = ra;
        *(uint4*)&dst[(tid + 256) * 8] = rb;
    };

    // prologue: B chunk for it=0 (k=0, cs=0) + A tile for it=0
    {
        const int nt0 = nhalf * 2;
        const unsigned short* W0 = w_t + ((size_t)((g * 20 + nt0) * 16 + 0)) * 4096;
        const unsigned short* W1 = w_t + ((size_t)((g * 20 + nt0 + 1) * 16 + 0)) * 4096;
        gl_lds16(W0 + tid * 8,        &Bs[0][tid * 8]);
        gl_lds16(W0 + 2048 + tid * 8, &Bs[0][2048 + tid * 8]);
        gl_lds16(W1 + tid * 8,        &Bs[0][4096 + tid * 8]);
        gl_lds16(W1 + 2048 + tid * 8, &Bs[0][4096 + 2048 + tid * 8]);
    }
    load_meta(0);
    build_A(0, &As[0][0]);
    __syncthreads();

    f32x4 acc[4][8];
    #pragma unroll
    for (int i = 0; i < 4; i++)
        #pragma unroll
        for (int j = 0; j < 8; j++) acc[i][j] = (f32x4){0.f, 0.f, 0.f, 0.f};

    int buf = 0;
    for (int it = 0; it < 80; ++it) {
        const int it2 = it + 1;
        if (it2 < 80) {                      // prefetch next B chunk + build next A tile
            const int k2 = it2 >> 4, cs2 = it2 & 15;
            const int nt0 = k2 * 4 + nhalf * 2;
            const unsigned short* W0 = w_t + ((size_t)((g * 20 + nt0) * 16 + cs2)) * 4096;
            const unsigned short* W1 = w_t + ((size_t)((g * 20 + nt0 + 1) * 16 + cs2)) * 4096;
            unsigned short* bd = &Bs[buf ^ 1][0];
            gl_lds16(W0 + tid * 8,        bd + tid * 8);
            gl_lds16(W0 + 2048 + tid * 8, bd + 2048 + tid * 8);
            gl_lds16(W1 + tid * 8,        bd + 4096 + tid * 8);
            gl_lds16(W1 + 2048 + tid * 8, bd + 4096 + 2048 + tid * 8);
            if (cs2 == 0) load_meta(k2);
            build_A(cs2, &As[buf ^ 1][0]);
        }
        // compute from As[buf], Bs[buf]
        {
            bf16x8 af[4];
            #pragma unroll
            for (int i = 0; i < 4; i++)
                af[i] = *(const bf16x8*)&As[buf][((wr4 + i) * 64 + lane) * 8];
            const unsigned short* bsrc = &Bs[buf][imgsel * 4096];
            #pragma unroll
            for (int j = 0; j < 8; j++) {
                bf16x8 bj = *(const bf16x8*)&bsrc[(j * 16 + l15) * 32 + sw];
                #pragma unroll
                for (int i = 0; i < 4; i++)
                    acc[i][j] = __builtin_amdgcn_mfma_f32_16x16x32_bf16(af[i], bj, acc[i][j], 0, 0, 0);
            }
        }
        __syncthreads();
        buf ^= 1;
    }

    // epilogue: + conv_b, store h bf16
    #pragma unroll
    for (int j = 0; j < 8; j++) {
        const int col = g * 512 + nhalf * 256 + imgsel * 128 + j * 16 + l15;
        const float bias = conv_b[col];
        #pragma unroll
        for (int i = 0; i < 4; i++) {
            const int row0 = mt * 128 + (wave >> 1) * 64 + i * 16 + l4 * 4;
            #pragma unroll
            for (int rr = 0; rr < 4; rr++)
                h[(size_t)(row0 + rr) * Ww + col] = f2bf(acc[i][j][rr] + bias);
        }
    }
}

// ---------- kernel 3: LayerNorm + mask + pooled partials (no atomics). ----------
// Each block writes its 1024-ch partial sum row into `partial` (aliases dead x_bf).
__global__ __launch_bounds__(256) void lnpool_kernel(
    const unsigned short* __restrict__ h, const float* __restrict__ gamma,
    const float* __restrict__ maskf, float* __restrict__ partial)
{
    const int tid = threadIdx.x;
    const int wave = tid >> 6, lane = tid & 63;
    const int c0 = lane * 16;
    const int bl0 = blockIdx.x * 16 + wave * 4;

    float g16[16];
    #pragma unroll
    for (int j = 0; j < 4; j++) {
        float4 gv = *(const float4*)(gamma + c0 + j * 4);
        g16[j*4+0] = gv.x; g16[j*4+1] = gv.y; g16[j*4+2] = gv.z; g16[j*4+3] = gv.w;
    }
    float pacc[16];
    #pragma unroll
    for (int j = 0; j < 16; j++) pacc[j] = 0.f;

    #pragma unroll
    for (int r = 0; r < 4; r++) {
        const int bl = bl0 + r;
        const float m = maskf[bl];
        const uint4 ha = *(const uint4*)(h + (size_t)bl * Ww + c0);
        const uint4 hb = *(const uint4*)(h + (size_t)bl * Ww + c0 + 8);
        float hf[16];
        const unsigned* pw = (const unsigned*)&ha;
        #pragma unroll
        for (int j = 0; j < 4; j++) {
            union { unsigned u; float f; } lo, hi;
            lo.u = pw[j] << 16; hi.u = pw[j] & 0xffff0000u;
            hf[j*2] = lo.f; hf[j*2+1] = hi.f;
        }
        pw = (const unsigned*)&hb;
        #pragma unroll
        for (int j = 0; j < 4; j++) {
            union { unsigned u; float f; } lo, hi;
            lo.u = pw[j] << 16; hi.u = pw[j] & 0xffff0000u;
            hf[8+j*2] = lo.f; hf[8+j*2+1] = hi.f;
        }
        float s1 = 0.f, s2 = 0.f;
        #pragma unroll
        for (int j = 0; j < 16; j++) { s1 += hf[j]; s2 += hf[j] * hf[j]; }
        #pragma unroll
        for (int off = 32; off; off >>= 1) {
            s1 += __shfl_xor(s1, off);
            s2 += __shfl_xor(s2, off);
        }
        const float mu = s1 * (1.0f / 1024.0f);
        const float var = s2 * (1.0f / 1024.0f) - mu * mu;
        const float rstd = rsqrtf(var + 1e-5f) * m;       // mask by multiply (branch-free)
        #pragma unroll
        for (int j = 0; j < 16; j++) pacc[j] += (hf[j] - mu) * rstd * g16[j];
    }
    __shared__ float spool[4][1024];
    #pragma unroll
    for (int j = 0; j < 4; j++)
        *(float4*)&spool[wave][c0 + j * 4] = *(float4*)&pacc[j * 4];
    __syncthreads();
    const int ch = tid * 4;
    float4 a = *(float4*)&spool[0][ch];
    float4 bq = *(float4*)&spool[1][ch];
    float4 cq = *(float4*)&spool[2][ch];
    float4 dq = *(float4*)&spool[3][ch];
    float4 s; s.x = a.x + bq.x + cq.x + dq.x; s.y = a.y + bq.y + cq.y + dq.y;
    s.z = a.z + bq.z + cq.z + dq.z; s.w = a.w + bq.w + cq.w + dq.w;
    *(float4*)&partial[(size_t)blockIdx.x * 1024 + ch] = s;
}

// ---------- kernel 4: lengths + partial reduce + projection (1024 thr, 4-way rows) ----------
__global__ __launch_bounds__(1024) void final_kernel(
    const float* __restrict__ partial, const float* __restrict__ maskf,
    const float* __restrict__ beta, const float* __restrict__ proj_w,
    const float* __restrict__ proj_b, float* __restrict__ out)
{
    const int b = blockIdx.x;
    const int tid = threadIdx.x;           // 0..1023
    const int rc = tid >> 8;               // row-chunk 0..3 (32 rows each)
    const int ch = (tid & 255) * 4;        // channel base

    float4 ps = {0.f, 0.f, 0.f, 0.f};
    #pragma unroll 4
    for (int j = rc * 32; j < rc * 32 + 32; ++j) {
        float4 v = *(const float4*)&partial[(size_t)((b << 7) + j) * 1024 + ch];
        ps.x += v.x; ps.y += v.y; ps.z += v.z; ps.w += v.w;
    }
    float len = maskf[b * Ll + tid] + maskf[b * Ll + 1024 + tid];
    float4 pw = *(const float4*)&proj_w[ch];
    float dotP = ps.x * pw.x + ps.y * pw.y + ps.z * pw.z + ps.w * pw.w;
    float dotB = 0.f;
    if (rc == 0) {
        float4 bt = *(const float4*)&beta[ch];
        dotB = bt.x * pw.x + bt.y * pw.y + bt.z * pw.z + bt.w * pw.w;
    }
    for (int off = 32; off; off >>= 1) {
        len  += __shfl_down(len, off);
        dotP += __shfl_down(dotP, off);
        dotB += __shfl_down(dotB, off);
    }
    __shared__ float rl[16], rp[16], rb2[16];
    const int wave = tid >> 6, lane = tid & 63;
    if (lane == 0) { rl[wave] = len; rp[wave] = dotP; rb2[wave] = dotB; }
    __syncthreads();
    if (tid == 0) {
        float Lt = 0.f, Pt = 0.f, Bt = 0.f;
        #pragma unroll
        for (int wv = 0; wv < 16; ++wv) { Lt += rl[wv]; Pt += rp[wv]; Bt += rb2[wv]; }
        out[b] = Pt / fmaxf(Lt, 1.0f) + Bt + proj_b[0];
    }
}

// ---------- workspace layout (bytes, 16B-aligned) ----------
// maskf  @        0  (65536)
// (gap)  @    65536  (32784)
// pk     @    98320  (1310720)  [16384][5] float4
// w_t    @  1409040  (5242880)  640 images x 8KB (swizzled, r>>1 scheme)
// x_bf   @  6651920  (33554432) [16384][1024] bf16; REUSED as partial[1024][1024] f32 after gemm
// h      @ 40206352  (33554432) [16384][1024] bf16
// total 73,760,784 B  (identical to last passing run)

extern "C" void kernel_launch(void* const* d_in, const int* in_sizes, int n_in,
                              void* d_out, int out_size, void* d_ws, size_t ws_size,
                              hipStream_t stream)
{
    const float* x      = (const float*)d_in[0];
    const void*  mask   = d_in[1];
    const float* w_off  = (const float*)d_in[2];
    const float* b_off  = (const float*)d_in[3];
    const float* conv_w = (const float*)d_in[4];
    const float* conv_b = (const float*)d_in[5];
    const float* gamma  = (const float*)d_in[6];
    const float* beta   = (const float*)d_in[7];
    const float* proj_w = (const float*)d_in[8];
    const float* proj_b = (const float*)d_in[9];
    float* out = (float*)d_out;

    char* ws = (char*)d_ws;
    float* maskf         = (float*)(ws + 0);
    float4* pk           = (float4*)(ws + 98320);
    unsigned short* w_t  = (unsigned short*)(ws + 1409040);
    unsigned short* x_bf = (unsigned short*)(ws + 6651920);
    float* partial       = (float*)(ws + 6651920);   // aliases x_bf (dead after gemm)
    unsigned short* h    = (unsigned short*)(ws + 40206352);

    prep_kernel<<<4368, 256, 0, stream>>>(x, w_off, b_off, conv_w, mask,
                                          x_bf, pk, w_t, maskf);
    gemm_kernel<<<dim3(128, 2, 2), 256, 0, stream>>>(x_bf, w_t, pk, conv_b, h);
    lnpool_kernel<<<1024, 256, 0, stream>>>(h, gamma, maskf, partial);
    final_kernel<<<8, 1024, 0, stream>>>(partial, maskf, beta, proj_w, proj_b, out);
}

// Round 11
// 283.016 us; speedup vs baseline: 1.1356x; 1.1356x over previous
//
#include <hip/hip_runtime.h>
#include <hip/hip_bf16.h>

// Problem constants
constexpr int Bb = 8, Ll = 2048, Ww = 1024;
constexpr int BL = Bb * Ll;              // 16384

typedef short bf16x8 __attribute__((ext_vector_type(8)));
typedef float f32x4  __attribute__((ext_vector_type(4)));

// ---------- bf16 helpers ----------
__device__ inline unsigned short f2bf(float f) {
    union { float f; unsigned u; } v; v.f = f;
    unsigned u = v.u;
    unsigned r = (u + 0x7fffu + ((u >> 16) & 1u)) >> 16;
    return (unsigned short)r;
}
// lerp two packed bf16 pairs (lo=even ch, hi=odd ch) -> packed bf16 pair
__device__ inline unsigned lerp_pair(unsigned pa, unsigned pb, float w0, float w1) {
    union { unsigned u; float f; } alo, ahi, blo, bhi;
    alo.u = pa << 16;  ahi.u = pa & 0xffff0000u;
    blo.u = pb << 16;  bhi.u = pb & 0xffff0000u;
    float hlo = w0 * alo.f + w1 * blo.f;
    float hhi = w0 * ahi.f + w1 * bhi.f;
    union { __hip_bfloat162 h2; unsigned u; } r;
    r.h2 = __float22bfloat162_rn(float2{hlo, hhi});
    return r.u;
}

// ---------- async global->LDS, 16B per lane ----------
__device__ inline void gl_lds16(const unsigned short* g, unsigned short* l) {
    __builtin_amdgcn_global_load_lds(
        (const __attribute__((address_space(1))) unsigned int*)g,
        (__attribute__((address_space(3))) unsigned int*)l, 16, 0, 0);
}

// ---------- kernel 1: FUSED preprocessing ----------
// blocks [0, 4096)        : offsets path  (x -> x_bf, pk)   [w_off via LDS transpose]
// blocks [4096, 4352)     : wconv path    (conv_w -> w_t pre-tiled swizzled bf16)
// blocks [4352, 4368)     : mask path     (mask -> maskf; per-block local dtype detect)
__global__ __launch_bounds__(256) void prep_kernel(
    const float* __restrict__ x, const float* __restrict__ w_off, const float* __restrict__ b_off,
    const float* __restrict__ conv_w, const void* __restrict__ mraw,
    unsigned short* __restrict__ x_bf, float4* __restrict__ pk,
    unsigned short* __restrict__ w_t, float* __restrict__ maskf)
{
    const int blk = blockIdx.x;
    const int tid = threadIdx.x;
    __shared__ float wt[5][1024];     // transposed w_off (20 KB), offsets path only

    if (blk < 4096) {
        // ---- cooperative transposed load of w_off: coalesced float4 reads ----
        #pragma unroll
        for (int r = 0; r < 5; ++r) {
            const int f4 = tid + 256 * r;            // float4 index 0..1279
            float4 v = *(const float4*)&w_off[f4 * 4];
            const int idx = f4 * 4;
            const float* ve = (const float*)&v;
            #pragma unroll
            for (int e = 0; e < 4; ++e) {
                const int li = idx + e;
                wt[li % 5][li / 5] = ve[e];
            }
        }

        // ---- offsets + x -> bf16 (one wave per row) ----
        const int wave = tid >> 6, lane = tid & 63;
        const int bl = blk * 4 + wave;
        const int l = bl & (Ll - 1);
        const int c0 = lane * 16;

        const float* xr = x + (size_t)bl * Ww + c0;
        float4 v0 = *(const float4*)(xr + 0);
        float4 v1 = *(const float4*)(xr + 4);
        float4 v2 = *(const float4*)(xr + 8);
        float4 v3 = *(const float4*)(xr + 12);
        float xv[16] = { v0.x,v0.y,v0.z,v0.w, v1.x,v1.y,v1.z,v1.w,
                         v2.x,v2.y,v2.z,v2.w, v3.x,v3.y,v3.z,v3.w };

        uint4 pa, pb;
        unsigned* pu = (unsigned*)&pa;
        #pragma unroll
        for (int j = 0; j < 4; j++) pu[j] = (unsigned)f2bf(xv[j*2]) | ((unsigned)f2bf(xv[j*2+1]) << 16);
        pu = (unsigned*)&pb;
        #pragma unroll
        for (int j = 0; j < 4; j++) pu[j] = (unsigned)f2bf(xv[8+j*2]) | ((unsigned)f2bf(xv[8+j*2+1]) << 16);
        *(uint4*)&x_bf[(size_t)bl * Ww + c0]     = pa;
        *(uint4*)&x_bf[(size_t)bl * Ww + c0 + 8] = pb;

        // ---- re-scan row with stride-64 lane mapping (coalesced, L1-hot) ----
        float xs[16];
        const float* xrow = x + (size_t)bl * Ww;
        #pragma unroll
        for (int jj = 0; jj < 16; jj++) xs[jj] = xrow[lane + 64 * jj];

        __syncthreads();     // wt ready (uniform branch: all threads of block here)

        float acc[5] = {0.f, 0.f, 0.f, 0.f, 0.f};
        #pragma unroll
        for (int jj = 0; jj < 16; jj++) {
            const int c = lane + 64 * jj;
            #pragma unroll
            for (int k = 0; k < 5; k++) acc[k] += xs[jj] * wt[k][c];
        }
        #pragma unroll
        for (int k = 0; k < 5; k++)
            #pragma unroll
            for (int off = 32; off; off >>= 1) acc[k] += __shfl_xor(acc[k], off);

        if (lane < 5) {
            float s = (lane == 0) ? acc[0] : (lane == 1) ? acc[1] : (lane == 2) ? acc[2]
                    : (lane == 3) ? acc[3] : acc[4];
            s += b_off[lane];
            float offv = tanhf(s) * 2.0f;
            float pos = (float)l + (float)(lane - 2) + offv;
            float p0 = floorf(pos);
            float frac = pos - p0;
            int i0 = (int)p0;
            int i1 = i0 + 1;
            int ok0 = (i0 >= 0) && (i0 < Ll);
            int ok1 = (i1 >= 0) && (i1 < Ll);
            float4 pkv;
            pkv.x = __int_as_float(min(max(i0, 0), Ll - 1));
            pkv.y = __int_as_float(min(max(i1, 0), Ll - 1));
            pkv.z = ok0 ? (1.0f - frac) : 0.0f;
            pkv.w = ok1 ? frac : 0.0f;
            pk[bl * 5 + lane] = pkv;
        }
    } else if (blk < 4352) {
        // ---- conv_w fp32 [g][o][c][k] -> pre-tiled swizzled bf16 images ----
        // Swizzle uses row bits [2:1] so a 16-lane ds_read quarter spreads over all
        // 8 16B-groups 2x (2-way = free).
        int t = (blk - 4096) * 256 + tid;            // 0..65535
        int oct = t & 63;
        int o   = (t >> 6) & 511;
        int g   = t >> 15;
        const float* src = conv_w + ((size_t)(g * 512 + o) * 512 + oct * 8) * 5;
        float f[40];
        #pragma unroll
        for (int j = 0; j < 10; j++) *(float4*)&f[j * 4] = *(const float4*)&src[j * 4];
        int r = o & 127, ob = o >> 7, cs = oct >> 2, q = oct & 3;
        int base16 = ((g * 20 + ob) * 16 + cs) * 512 + r * 4 + (q ^ ((r >> 1) & 3));
        #pragma unroll
        for (int k = 0; k < 5; k++) {
            ushort4 lo, hi;
            lo.x = f2bf(f[0 * 5 + k]); lo.y = f2bf(f[1 * 5 + k]);
            lo.z = f2bf(f[2 * 5 + k]); lo.w = f2bf(f[3 * 5 + k]);
            hi.x = f2bf(f[4 * 5 + k]); hi.y = f2bf(f[5 * 5 + k]);
            hi.z = f2bf(f[6 * 5 + k]); hi.w = f2bf(f[7 * 5 + k]);
            int dst16 = base16 + k * 4 * 16 * 512;
            *(ushort4*)&w_t[(size_t)dst16 * 8]     = lo;
            *(ushort4*)&w_t[(size_t)dst16 * 8 + 4] = hi;
        }
    } else {
        // ---- mask expand; each block re-derives dtype flags locally (no cross-block dep)
        const unsigned char* mb = (const unsigned char*)mraw;
        const unsigned* mw = (const unsigned*)mraw;
        int nonint = 0, notf = 0, hasf = 0;
        for (int i = tid; i < BL; i += 256) { if ((i & 3) && mb[i]) nonint = 1; }
        for (int i = tid; i < BL / 4; i += 256) {
            unsigned w = mw[i];
            if (w == 0x3f800000u) hasf = 1; else if (w) notf = 1;
        }
        __shared__ int sf[3];
        if (tid == 0) { sf[0] = 0; sf[1] = 0; sf[2] = 0; }
        __syncthreads();
        if (nonint) atomicOr(&sf[0], 1);
        if (notf)   atomicOr(&sf[1], 1);
        if (hasf)   atomicOr(&sf[2], 1);
        __syncthreads();
        const int is_f32  = (!sf[1]) && sf[2];
        const int is_bool = (!is_f32) && sf[0];
        const int gid = (blk - 4352) * 256 + tid;    // 4096 threads total over 16 blocks
        for (int i = gid; i < BL; i += 4096) {
            int masked = is_bool ? (mb[i] != 0) : (mw[i] != 0u);
            maskf[i] = masked ? 0.0f : 1.0f;
        }
    }
}

// ---------- kernel 2: fused deform GEMM -> h. Block = 64 rows x 256 cols. ----------
// R9-proven structure (LDS A-build, runtime buf, __syncthreads, conflict-free B
// swizzle, 3 blocks/CU) + XCD-aware 1D block swizzle: the 4 blocks sharing an mt
// row-tile (2 nhalf x 2 g) get linear IDs congruent mod 8, so round-robin dispatch
// co-locates them on one XCD and their shared x_bf row-gathers hit that XCD's L2.
// id = ((mt/8)*4 + sub)*8 + mt%8  (bijective over 1024).
__global__ __launch_bounds__(256, 2) void gemm_kernel(
    const unsigned short* __restrict__ x_bf, const unsigned short* __restrict__ w_t,
    const float4* __restrict__ pk, const float* __restrict__ conv_b,
    unsigned short* __restrict__ h)
{
    __shared__ unsigned short Bs[2][2 * 4096];   // 2 x 16KB = 32 KB
    __shared__ unsigned short As[2][2048];       // 2 x  4KB =  8 KB
    const int tid = threadIdx.x;
    // decode XCD swizzle
    const int id   = blockIdx.x;          // 0..1023
    const int xcd  = id & 7;
    const int slot = id >> 3;
    const int mt   = (slot >> 2) * 8 + xcd;   // 0..255 (64-row tiles)
    const int sub  = slot & 3;
    const int nhalf = sub >> 1;           // 0..1
    const int g     = sub & 1;            // 0..1
    const int b = mt >> 5;                // 32 tiles per batch element
    const int lane = tid & 63, wave = tid >> 6;
    const int wr16 = (wave >> 1) * 2;     // 16-row-group base for compute (0 or 2)
    const int imgsel = wave & 1;          // column 128-block within the 256
    const int l15 = lane & 15, l4 = lane >> 4;
    const int sw = (l4 ^ ((l15 >> 1) & 3)) * 8;   // conflict-free B-read swizzle

    // builder role: this thread fills chunk tid of the A tile (one row, one octet)
    const int arow = ((tid >> 6) << 4) + (tid & 15);   // 0..63
    const int oct8 = ((tid >> 4) & 3) * 8;             // ch-octet within 32-chunk
    const int bl_a = mt * 64 + arow;
    const int gbase = g * 512;

    unsigned off0a, off1a;
    float w0a, w1a;
    auto load_meta = [&](int k2) {
        float4 pa = pk[bl_a * 5 + k2];
        off0a = (unsigned)(((b << 11) + __float_as_int(pa.x)) * Ww + gbase);
        off1a = (unsigned)(((b << 11) + __float_as_int(pa.y)) * Ww + gbase);
        w0a = pa.z; w1a = pa.w;
    };
    auto build_A = [&](int cs2, unsigned short* dst) {
        const int ch = cs2 * 32 + oct8;
        uint4 ua = *(const uint4*)(x_bf + off0a + ch);
        uint4 ub = *(const uint4*)(x_bf + off1a + ch);
        uint4 ra;
        ra.x = lerp_pair(ua.x, ub.x, w0a, w1a);
        ra.y = lerp_pair(ua.y, ub.y, w0a, w1a);
        ra.z = lerp_pair(ua.z, ub.z, w0a, w1a);
        ra.w = lerp_pair(ua.w, ub.w, w0a, w1a);
        *(uint4*)&dst[tid * 8] = ra;
    };

    // prologue: B chunk for it=0 (k=0, cs=0) + A tile for it=0
    {
        const int nt0 = nhalf * 2;
        const unsigned short* W0 = w_t + ((size_t)((g * 20 + nt0) * 16 + 0)) * 4096;
        const unsigned short* W1 = w_t + ((size_t)((g * 20 + nt0 + 1) * 16 + 0)) * 4096;
        gl_lds16(W0 + tid * 8,        &Bs[0][tid * 8]);
        gl_lds16(W0 + 2048 + tid * 8, &Bs[0][2048 + tid * 8]);
        gl_lds16(W1 + tid * 8,        &Bs[0][4096 + tid * 8]);
        gl_lds16(W1 + 2048 + tid * 8, &Bs[0][4096 + 2048 + tid * 8]);
    }
    load_meta(0);
    build_A(0, &As[0][0]);
    __syncthreads();

    f32x4 acc[2][8];
    #pragma unroll
    for (int i = 0; i < 2; i++)
        #pragma unroll
        for (int j = 0; j < 8; j++) acc[i][j] = (f32x4){0.f, 0.f, 0.f, 0.f};

    int buf = 0;
    for (int it = 0; it < 80; ++it) {
        const int it2 = it + 1;
        if (it2 < 80) {                      // prefetch next B chunk + build next A tile
            const int k2 = it2 >> 4, cs2 = it2 & 15;
            const int nt0 = k2 * 4 + nhalf * 2;
            const unsigned short* W0 = w_t + ((size_t)((g * 20 + nt0) * 16 + cs2)) * 4096;
            const unsigned short* W1 = w_t + ((size_t)((g * 20 + nt0 + 1) * 16 + cs2)) * 4096;
            unsigned short* bd = &Bs[buf ^ 1][0];
            gl_lds16(W0 + tid * 8,        bd + tid * 8);
            gl_lds16(W0 + 2048 + tid * 8, bd + 2048 + tid * 8);
            gl_lds16(W1 + tid * 8,        bd + 4096 + tid * 8);
            gl_lds16(W1 + 2048 + tid * 8, bd + 4096 + 2048 + tid * 8);
            if (cs2 == 0) load_meta(k2);
            build_A(cs2, &As[buf ^ 1][0]);
        }
        // compute from As[buf], Bs[buf]
        {
            bf16x8 af[2];
            #pragma unroll
            for (int i = 0; i < 2; i++)
                af[i] = *(const bf16x8*)&As[buf][((wr16 + i) * 64 + lane) * 8];
            const unsigned short* bsrc = &Bs[buf][imgsel * 4096];
            #pragma unroll
            for (int j = 0; j < 8; j++) {
                bf16x8 bj = *(const bf16x8*)&bsrc[(j * 16 + l15) * 32 + sw];
                #pragma unroll
                for (int i = 0; i < 2; i++)
                    acc[i][j] = __builtin_amdgcn_mfma_f32_16x16x32_bf16(af[i], bj, acc[i][j], 0, 0, 0);
            }
        }
        __syncthreads();
        buf ^= 1;
    }

    // epilogue: + conv_b, store h bf16
    #pragma unroll
    for (int j = 0; j < 8; j++) {
        const int col = g * 512 + nhalf * 256 + imgsel * 128 + j * 16 + l15;
        const float bias = conv_b[col];
        #pragma unroll
        for (int i = 0; i < 2; i++) {
            const int row0 = mt * 64 + (wave >> 1) * 32 + i * 16 + l4 * 4;
            #pragma unroll
            for (int rr = 0; rr < 4; rr++)
                h[(size_t)(row0 + rr) * Ww + col] = f2bf(acc[i][j][rr] + bias);
        }
    }
}

// ---------- kernel 3: LayerNorm + mask + pooled partials (no atomics). ----------
// Each block writes its 1024-ch partial sum row into `partial` (aliases dead x_bf).
__global__ __launch_bounds__(256) void lnpool_kernel(
    const unsigned short* __restrict__ h, const float* __restrict__ gamma,
    const float* __restrict__ maskf, float* __restrict__ partial)
{
    const int tid = threadIdx.x;
    const int wave = tid >> 6, lane = tid & 63;
    const int c0 = lane * 16;
    const int bl0 = blockIdx.x * 16 + wave * 4;

    float g16[16];
    #pragma unroll
    for (int j = 0; j < 4; j++) {
        float4 gv = *(const float4*)(gamma + c0 + j * 4);
        g16[j*4+0] = gv.x; g16[j*4+1] = gv.y; g16[j*4+2] = gv.z; g16[j*4+3] = gv.w;
    }
    float pacc[16];
    #pragma unroll
    for (int j = 0; j < 16; j++) pacc[j] = 0.f;

    #pragma unroll
    for (int r = 0; r < 4; r++) {
        const int bl = bl0 + r;
        const float m = maskf[bl];
        const uint4 ha = *(const uint4*)(h + (size_t)bl * Ww + c0);
        const uint4 hb = *(const uint4*)(h + (size_t)bl * Ww + c0 + 8);
        float hf[16];
        const unsigned* pw = (const unsigned*)&ha;
        #pragma unroll
        for (int j = 0; j < 4; j++) {
            union { unsigned u; float f; } lo, hi;
            lo.u = pw[j] << 16; hi.u = pw[j] & 0xffff0000u;
            hf[j*2] = lo.f; hf[j*2+1] = hi.f;
        }
        pw = (const unsigned*)&hb;
        #pragma unroll
        for (int j = 0; j < 4; j++) {
            union { unsigned u; float f; } lo, hi;
            lo.u = pw[j] << 16; hi.u = pw[j] & 0xffff0000u;
            hf[8+j*2] = lo.f; hf[8+j*2+1] = hi.f;
        }
        float s1 = 0.f, s2 = 0.f;
        #pragma unroll
        for (int j = 0; j < 16; j++) { s1 += hf[j]; s2 += hf[j] * hf[j]; }
        #pragma unroll
        for (int off = 32; off; off >>= 1) {
            s1 += __shfl_xor(s1, off);
            s2 += __shfl_xor(s2, off);
        }
        const float mu = s1 * (1.0f / 1024.0f);
        const float var = s2 * (1.0f / 1024.0f) - mu * mu;
        const float rstd = rsqrtf(var + 1e-5f) * m;       // mask by multiply (branch-free)
        #pragma unroll
        for (int j = 0; j < 16; j++) pacc[j] += (hf[j] - mu) * rstd * g16[j];
    }
    __shared__ float spool[4][1024];
    #pragma unroll
    for (int j = 0; j < 4; j++)
        *(float4*)&spool[wave][c0 + j * 4] = *(float4*)&pacc[j * 4];
    __syncthreads();
    const int ch = tid * 4;
    float4 a = *(float4*)&spool[0][ch];
    float4 bq = *(float4*)&spool[1][ch];
    float4 cq = *(float4*)&spool[2][ch];
    float4 dq = *(float4*)&spool[3][ch];
    float4 s; s.x = a.x + bq.x + cq.x + dq.x; s.y = a.y + bq.y + cq.y + dq.y;
    s.z = a.z + bq.z + cq.z + dq.z; s.w = a.w + bq.w + cq.w + dq.w;
    *(float4*)&partial[(size_t)blockIdx.x * 1024 + ch] = s;
}

// ---------- kernel 4: lengths + partial reduce + projection (1024 thr, 4-way rows) ----------
__global__ __launch_bounds__(1024) void final_kernel(
    const float* __restrict__ partial, const float* __restrict__ maskf,
    const float* __restrict__ beta, const float* __restrict__ proj_w,
    const float* __restrict__ proj_b, float* __restrict__ out)
{
    const int b = blockIdx.x;
    const int tid = threadIdx.x;           // 0..1023
    const int rc = tid >> 8;               // row-chunk 0..3 (32 rows each)
    const int ch = (tid & 255) * 4;        // channel base

    float4 ps = {0.f, 0.f, 0.f, 0.f};
    #pragma unroll 4
    for (int j = rc * 32; j < rc * 32 + 32; ++j) {
        float4 v = *(const float4*)&partial[(size_t)((b << 7) + j) * 1024 + ch];
        ps.x += v.x; ps.y += v.y; ps.z += v.z; ps.w += v.w;
    }
    float len = maskf[b * Ll + tid] + maskf[b * Ll + 1024 + tid];
    float4 pw = *(const float4*)&proj_w[ch];
    float dotP = ps.x * pw.x + ps.y * pw.y + ps.z * pw.z + ps.w * pw.w;
    float dotB = 0.f;
    if (rc == 0) {
        float4 bt = *(const float4*)&beta[ch];
        dotB = bt.x * pw.x + bt.y * pw.y + bt.z * pw.z + bt.w * pw.w;
    }
    for (int off = 32; off; off >>= 1) {
        len  += __shfl_down(len, off);
        dotP += __shfl_down(dotP, off);
        dotB += __shfl_down(dotB, off);
    }
    __shared__ float rl[16], rp[16], rb2[16];
    const int wave = tid >> 6, lane = tid & 63;
    if (lane == 0) { rl[wave] = len; rp[wave] = dotP; rb2[wave] = dotB; }
    __syncthreads();
    if (tid == 0) {
        float Lt = 0.f, Pt = 0.f, Bt = 0.f;
        #pragma unroll
        for (int wv = 0; wv < 16; ++wv) { Lt += rl[wv]; Pt += rp[wv]; Bt += rb2[wv]; }
        out[b] = Pt / fmaxf(Lt, 1.0f) + Bt + proj_b[0];
    }
}

// ---------- workspace layout (bytes, 16B-aligned) ----------
// maskf  @        0  (65536)
// (gap)  @    65536  (32784)
// pk     @    98320  (1310720)  [16384][5] float4
// w_t    @  1409040  (5242880)  640 images x 8KB (swizzled, r>>1 scheme)
// x_bf   @  6651920  (33554432) [16384][1024] bf16; REUSED as partial[1024][1024] f32 after gemm
// h      @ 40206352  (33554432) [16384][1024] bf16
// total 73,760,784 B  (identical to last passing run)

extern "C" void kernel_launch(void* const* d_in, const int* in_sizes, int n_in,
                              void* d_out, int out_size, void* d_ws, size_t ws_size,
                              hipStream_t stream)
{
    const float* x      = (const float*)d_in[0];
    const void*  mask   = d_in[1];
    const float* w_off  = (const float*)d_in[2];
    const float* b_off  = (const float*)d_in[3];
    const float* conv_w = (const float*)d_in[4];
    const float* conv_b = (const float*)d_in[5];
    const float* gamma  = (const float*)d_in[6];
    const float* beta   = (const float*)d_in[7];
    const float* proj_w = (const float*)d_in[8];
    const float* proj_b = (const float*)d_in[9];
    float* out = (float*)d_out;

    char* ws = (char*)d_ws;
    float* maskf         = (float*)(ws + 0);
    float4* pk           = (float4*)(ws + 98320);
    unsigned short* w_t  = (unsigned short*)(ws + 1409040);
    unsigned short* x_bf = (unsigned short*)(ws + 6651920);
    float* partial       = (float*)(ws + 6651920);   // aliases x_bf (dead after gemm)
    unsigned short* h    = (unsigned short*)(ws + 40206352);

    prep_kernel<<<4368, 256, 0, stream>>>(x, w_off, b_off, conv_w, mask,
                                          x_bf, pk, w_t, maskf);
    gemm_kernel<<<1024, 256, 0, stream>>>(x_bf, w_t, pk, conv_b, h);
    lnpool_kernel<<<1024, 256, 0, stream>>>(h, gamma, maskf, partial);
    final_kernel<<<8, 1024, 0, stream>>>(partial, maskf, beta, proj_w, proj_b, out);
}